// Round 13
// baseline (354.783 us; speedup 1.0000x reference)
//
#include <hip/hip_runtime.h>
#include <stdint.h>

#define NB   16
#define CD   256
#define HW   1024
#define NQ   16384
#define KCN  8192

typedef unsigned long long u64;
typedef unsigned short     u16;
using f32x4  = __attribute__((ext_vector_type(4))) float;
using bf16x8 = __attribute__((ext_vector_type(8))) __bf16;

// ---------------- workspace layout (~16.9 MB) ----------------
#define ZTB_OFF  0            // u16  [NQ][CD]    8 MB  (z transposed, bf16)
#define EMBB_OFF 8388608      // u16  [KCN][CD]   4 MB  (emb, bf16)
#define EH_OFF   12582912     // f32  [KCN]      32 KB  (||e||^2/2 + 1024)
#define CAND_OFF 12615680     // u64  [NQ][32]    4 MB  (8 splits x 2 halves x top-2)

static __device__ __forceinline__ void gl_lds16(const void* g, void* l) {
  __builtin_amdgcn_global_load_lds(
      (const __attribute__((address_space(1))) void*)g,
      (__attribute__((address_space(3))) void*)l, 16, 0, 0);
}

static __device__ __forceinline__ unsigned bf16r(float x) {  // RNE fp32->bf16 bits
  unsigned u = __float_as_uint(x);
  return (u + 0x7fffu + ((u >> 16) & 1u)) >> 16;
}

static __device__ __forceinline__ u64 umin64(u64 a, u64 b) { return a < b ? a : b; }
static __device__ __forceinline__ u64 umax64(u64 a, u64 b) { return a < b ? b : a; }

// ---------------- kernel 1: merged prep (R18 version — best measured) ---------
__global__ __launch_bounds__(256) void k_prep(const float* __restrict__ z,
                                              const float* __restrict__ emb,
                                              u16* __restrict__ zTb,
                                              u16* __restrict__ embB,
                                              float* __restrict__ eH) {
  const int bx = (int)blockIdx.x;
  if (bx < 1024) {
    __shared__ float tile[64][65];
    const int b   = bx >> 6;
    const int hwT = (bx >> 2) & 15;
    const int cT  = bx & 3;
    const int tx  = threadIdx.x & 63;
    const int ty  = threadIdx.x >> 6;
    const float* src = z + (size_t)(b * CD + cT * 64) * HW + hwT * 64;
#pragma unroll
    for (int i = 0; i < 16; ++i) {
      const int c_l = ty + 4 * i;
      tile[c_l][tx] = src[(size_t)c_l * HW + tx];
    }
    __syncthreads();
    const size_t dbase = (size_t)(b * HW + hwT * 64) * CD + cT * 64;
    const int rsub = tx >> 4;        // 0..3
    const int cq   = (tx & 15) * 4;  // c_local quad base
#pragma unroll
    for (int i = 0; i < 4; ++i) {
      const int r = ty * 16 + i * 4 + rsub;   // hw_local
      ushort4 pk;
      pk.x = (u16)bf16r(tile[cq + 0][r]);
      pk.y = (u16)bf16r(tile[cq + 1][r]);
      pk.z = (u16)bf16r(tile[cq + 2][r]);
      pk.w = (u16)bf16r(tile[cq + 3][r]);
      *(ushort4*)(zTb + dbase + (size_t)r * CD + cq) = pk;
    }
  } else {
    const int wave = (bx - 1024) * 4 + ((int)threadIdx.x >> 6);  // 0..1023
    const int lane = threadIdx.x & 63;
#pragma unroll
    for (int it = 0; it < 8; ++it) {
      const int row = wave * 8 + it;
      const float4 v = *(const float4*)(emb + (size_t)row * CD + lane * 4);
      uint2 pk;
      pk.x = bf16r(v.x) | (bf16r(v.y) << 16);
      pk.y = bf16r(v.z) | (bf16r(v.w) << 16);
      *(uint2*)(embB + (size_t)row * CD + lane * 4) = pk;
      float s = v.x * v.x + v.y * v.y + v.z * v.z + v.w * v.w;
#pragma unroll
      for (int off = 32; off; off >>= 1) s += __shfl_xor(s, off, 64);
      if (lane == 0) eH[row] = 0.5f * s + 1024.0f;
    }
  }
}

// ---------------- kernel 2: R20 — 8-wave blocks, 48KB ring-3, 24 waves/CU -----
// Every plateau variant ran 8 waves/CU (2 blocks). Per-CU ledger: LDS-read time
// per interval ~0.8x MFMA time -> needs cross-block wave interleave to cover;
// 2 blocks/CU gives almost none. R20: 512-thr blocks (4 qg x 2 nh waves),
// Q=32/wave (Af 64 VGPR), acc 32, ~150 regs -> (512,6) cap 341 no spill;
// ring-3 x 16KB = 48KB -> 3 blocks/CU = 24 waves/CU (3x wave cover).
// Staging: thread t, DMA u: row = u*64 + (t>>3), slot3 = t&7, granule =
// slot3^(row&7) (0-conflict layout, R11-proven). vmcnt ledger (2-DMA stages,
// 4-load eh; invariant entering nt: [cA(2),cB(2)]=4):
//  kc0: WAITV(2)->cA | bar | STAGE p2<-(nt,2), eh | MFMA p0      q=[cB,cC,eh]=8
//  kc1: WAITV(6)->cB | bar | STAGE p0<-(nt,3)     | MFMA p1      q=[cC,eh,cD]=8
//  kc2: WAITV(6)->cC | bar | STAGE p1<-(nt+1,0)   | MFMA p2      q=[eh,cD,cE]=8
//  kc3: WAITV(2)->eh+cD | bar | STAGE p2<-(nt+1,1)| MFMA p0 | EPI q=[cE,cF]=4 ✓
// rotate (p0,p1,p2)<-(p1,p2,p0). Peel nt7: {2,6,6,0}, stages (7,2),(7,3) only.
// Buckets (split,nh-512) top-2, id = nt*4+j (5 bits, &~31u — R12-proven),
// cand layout unchanged; k_prep/k_pick_out = R18.

#define WAITV(N) asm volatile("s_waitcnt vmcnt(" #N ")" ::: "memory")
#define MEMFENCE() asm volatile("" ::: "memory")

__global__ __launch_bounds__(512, 6) void k_argmin(const u16* __restrict__ zTb,
                                                   const u16* __restrict__ embB,
                                                   const float* __restrict__ eH,
                                                   u64* __restrict__ cand) {
  __shared__ __align__(16) u16 Bs[3][128 * 64];   // 3 ring slots x 16 KB = 48 KB

  const int tid  = (int)threadIdx.x;
  const int w    = tid >> 6;       // 0..7
  const int lane = tid & 63;
  const int l15  = lane & 15, quad = lane >> 4;
  const int q0    = (int)(blockIdx.x >> 3) * 128;
  const int split = (int)(blockIdx.x & 7);
  const int qg = w & 3;            // q-group: rows q0+qg*32 .. +32
  const int nh = w >> 2;           // n-half (bucket): 64 rows per nt

  // ---- A fragments resident (64 VGPR):
  // Af[i][kc][ks][lane(quad,l15)] = A[q0+qg*32+i*16+l15][kc*64+ks*32+quad*8 ..+7]
  bf16x8 Af[2][4][2];
  {
    const char* aB = (const char*)zTb + (size_t)(q0 + qg * 32 + l15) * 512 + quad * 16;
#pragma unroll
    for (int i = 0; i < 2; ++i)
#pragma unroll
      for (int kc = 0; kc < 4; ++kc)
#pragma unroll
        for (int ks = 0; ks < 2; ++ks)
          Af[i][kc][ks] = *(const bf16x8*)(aB + i * 8192 + kc * 128 + ks * 64);
  }
  MEMFENCE();   // A loads oldest in the vmcnt queue

  // ---- B staging: thread t, DMA u in {0,1}: LDS byte u*8192 + t*16
  // -> row = u*64 + (t>>3), slot3 = t&7; src granule = slot3 ^ (row&7)
  // (row&7 = (t>>3)&7 for both u since 64 ≡ 0 mod 8)
  const char* bS = (const char*)embB + (size_t)split * 524288
                 + (size_t)(tid >> 3) * 512
                 + (size_t)(((tid & 7) ^ ((tid >> 3) & 7)) * 16);
  const int ldsW = tid * 16;

#define STAGEP(P_, NT_, KC_)                                                   \
  do {                                                                         \
    const char* _s = bS + (NT_) * 65536 + (KC_) * 128;                         \
    char* _d = (char*)(P_) + ldsW;                                             \
    gl_lds16(_s,         _d);                                                  \
    gl_lds16(_s + 32768, _d + 8192);                                           \
    MEMFENCE();                                                                \
  } while (0)

  // frag reads: n = nh*64 + j*16 + l15 (n&7 = l15&7), granule ks*4+quad at
  // slot3 = (ks*4+quad)^(l15&7); ks flips slot bit2 -> byte XOR 64
  const int bR0 = (nh * 64 + l15) * 128 + ((quad ^ (l15 & 7)) * 16);
  const int bR1 = bR0 ^ 64;

  f32x4 acc[2][4];
  float b1[8], b2[8];
  const float FMAX = __uint_as_float(0x7F7FFFFFu);
#pragma unroll
  for (int s = 0; s < 8; ++s) { b1[s] = FMAX; b2[s] = FMAX; }

  char* p0 = (char*)Bs[0];
  char* p1 = (char*)Bs[1];
  char* p2 = (char*)Bs[2];

  // prologue: (0,0)->p0, (0,1)->p1 ; queue = 4 (after A drained)
  STAGEP(p0, 0, 0);
  STAGEP(p1, 0, 1);

#define MFMA_P(P_, KC_)                                                        \
  do {                                                                         \
    const char* _b = (const char*)(P_);                                        \
    _Pragma("unroll")                                                          \
    for (int ks = 0; ks < 2; ++ks) {                                           \
      bf16x8 bfr[4];                                                           \
      const int _o = ks ? bR1 : bR0;                                           \
      _Pragma("unroll")                                                        \
      for (int j = 0; j < 4; ++j)                                              \
        bfr[j] = *(const bf16x8*)(_b + j * 2048 + _o);                         \
      __builtin_amdgcn_s_setprio(1);                                           \
      _Pragma("unroll")                                                        \
      for (int i = 0; i < 2; ++i)                                              \
        _Pragma("unroll")                                                      \
        for (int j = 0; j < 4; ++j)                                            \
          acc[i][j] = __builtin_amdgcn_mfma_f32_16x16x32_bf16(                 \
              Af[i][KC_][ks], bfr[j], acc[i][j], 0, 0, 0);                     \
      __builtin_amdgcn_s_setprio(0);                                           \
    }                                                                          \
  } while (0)

#define EPILOGUE(NT_)                                                          \
  do {                                                                         \
    _Pragma("unroll")                                                          \
    for (int i = 0; i < 2; ++i)                                                \
      _Pragma("unroll")                                                        \
      for (int r = 0; r < 4; ++r) {                                            \
        const int s = i * 4 + r;                                               \
        float kq[4];                                                           \
        _Pragma("unroll")                                                      \
        for (int j = 0; j < 4; ++j)                                            \
          kq[j] = __uint_as_float(                                             \
              (__float_as_uint(eh[j] - acc[i][j][r]) & ~31u)                   \
              | (unsigned)((NT_) * 4 + j));                                    \
        const float lo01 = fminf(kq[0], kq[1]), hi01 = fmaxf(kq[0], kq[1]);    \
        const float lo23 = fminf(kq[2], kq[3]), hi23 = fmaxf(kq[2], kq[3]);    \
        const float best = fminf(lo01, lo23);                                  \
        const float sec  = fminf(fmaxf(lo01, lo23), fminf(hi01, hi23));        \
        b2[s] = fminf(fmaxf(best, b1[s]), fminf(sec, b2[s]));                  \
        b1[s] = fminf(best, b1[s]);                                            \
      }                                                                        \
  } while (0)

  float eh[4];
  const float* ehP = eH + split * 1024 + nh * 64 + l15;

  for (int nt = 0; nt < 7; ++nt) {
#pragma unroll
    for (int i = 0; i < 2; ++i)
#pragma unroll
      for (int j = 0; j < 4; ++j) acc[i][j] = f32x4{0.f, 0.f, 0.f, 0.f};

    WAITV(2); __builtin_amdgcn_s_barrier(); MEMFENCE();   // (nt,0) done
    STAGEP(p2, nt, 2);
#pragma unroll
    for (int j = 0; j < 4; ++j) eh[j] = ehP[nt * 128 + j * 16];
    MEMFENCE();
    MFMA_P(p0, 0);

    WAITV(6); __builtin_amdgcn_s_barrier(); MEMFENCE();   // (nt,1) done
    STAGEP(p0, nt, 3);
    MFMA_P(p1, 1);

    WAITV(6); __builtin_amdgcn_s_barrier(); MEMFENCE();   // (nt,2) done
    STAGEP(p1, nt + 1, 0);
    MFMA_P(p2, 2);

    WAITV(2); __builtin_amdgcn_s_barrier(); MEMFENCE();   // eh + (nt,3) done
    STAGEP(p2, nt + 1, 1);
    MFMA_P(p0, 3);

    EPILOGUE(nt);

    char* tmp = p0; p0 = p1; p1 = p2; p2 = tmp;
  }

  // ---- peeled nt = 7: waits {2,6,6,0}; stages only (7,2),(7,3)
  {
#pragma unroll
    for (int i = 0; i < 2; ++i)
#pragma unroll
      for (int j = 0; j < 4; ++j) acc[i][j] = f32x4{0.f, 0.f, 0.f, 0.f};

    WAITV(2); __builtin_amdgcn_s_barrier(); MEMFENCE();
    STAGEP(p2, 7, 2);
#pragma unroll
    for (int j = 0; j < 4; ++j) eh[j] = ehP[7 * 128 + j * 16];
    MEMFENCE();
    MFMA_P(p0, 0);

    WAITV(6); __builtin_amdgcn_s_barrier(); MEMFENCE();
    STAGEP(p0, 7, 3);
    MFMA_P(p1, 1);

    WAITV(6); __builtin_amdgcn_s_barrier(); MEMFENCE();
    MFMA_P(p2, 2);

    WAITV(0); __builtin_amdgcn_s_barrier(); MEMFENCE();
    MFMA_P(p0, 3);

    EPILOGUE(7);
  }
#undef STAGEP
#undef MFMA_P
#undef EPILOGUE

  // ---- per-wave: u64 butterfly top-2 merge over 16-lane groups, write cand
#pragma unroll
  for (int s = 0; s < 8; ++s) {
    u64 x1 = ((u64)__float_as_uint(b1[s]) << 32) | (unsigned)l15;
    u64 x2 = ((u64)__float_as_uint(b2[s]) << 32) | (unsigned)l15;
#pragma unroll
    for (int off = 1; off < 16; off <<= 1) {
      const u64 o1 = __shfl_xor(x1, off, 64);
      const u64 o2 = __shfl_xor(x2, off, 64);
      const u64 lo = umin64(x1, o1);
      const u64 hi = umax64(x1, o1);
      x1 = lo;
      x2 = umin64(hi, umin64(x2, o2));
    }
    if (l15 == 0) {
      const int i = s >> 2, r = s & 3;
      const int q = q0 + qg * 32 + i * 16 + quad * 4 + r;
      const unsigned kb1 = (unsigned)(x1 >> 32), kb2 = (unsigned)(x2 >> 32);
      // id = nt*4 + j (5 bits): n = split*1024 + nt*128 + nh*64 + j*16 + col
      const int id1 = (int)(kb1 & 31u), id2 = (int)(kb2 & 31u);
      const int n1 = split * 1024 + (id1 >> 2) * 128 + nh * 64
                     + (id1 & 3) * 16 + (int)(x1 & 15);
      const int n2 = split * 1024 + (id2 >> 2) * 128 + nh * 64
                     + (id2 & 3) * 16 + (int)(x2 & 15);
      cand[(size_t)q * 32 + split * 4 + nh * 2 + 0] = ((u64)kb1 << 32) | (unsigned)n1;
      cand[(size_t)q * 32 + split * 4 + nh * 2 + 1] = ((u64)kb2 << 32) | (unsigned)n2;
    }
  }
}

// ---------------- kernel 3: coalesced pick_out, 1024 threads (R18 version) ----
__global__ __launch_bounds__(1024) void k_pick_out(const float* __restrict__ z,
                                                   const float* __restrict__ emb,
                                                   const u64* __restrict__ cand,
                                                   float* __restrict__ out) {
  __shared__ float zs[256][66];   // 67.6 KB
  const int t    = (int)threadIdx.x;
  const int lane = t & 63;
  const int wv   = t >> 6;        // 0..15
  const int l15  = t & 15;
  const int g    = t >> 4;        // 0..63 : query group
  const int q0b  = (int)blockIdx.x * 64;
  const int b    = q0b >> 10, hw0 = q0b & 1023;

  // ---- phase 0: wave wv stages channels [wv*16, wv*16+16), float2 per lane
  {
    const int hw   = (lane & 31) * 2;
    const int csub = lane >> 5;     // 0..1
#pragma unroll
    for (int i = 0; i < 8; ++i) {
      const int c = wv * 16 + i * 2 + csub;
      const float2 v = *(const float2*)(z + ((size_t)(b * CD + c)) * HW + hw0 + hw);
      *(float2*)&zs[c][hw] = v;
    }
  }
  __syncthreads();

  // ---- phase 1: top-4-of-32 select for query q = q0b + g
  const int q = q0b + g;
  const u64* cp = cand + (size_t)q * 32 + l15 * 2;
  const u64 v0 = cp[0], v1 = cp[1];
  u64 s0 = umin64(v0, v1), s1 = umax64(v0, v1), s2 = ~0ull, s3 = ~0ull;
#pragma unroll
  for (int off = 1; off < 16; off <<= 1) {
    const u64 b0 = __shfl_xor(s0, off, 64);
    const u64 b1 = __shfl_xor(s1, off, 64);
    const u64 b2 = __shfl_xor(s2, off, 64);
    const u64 b3 = __shfl_xor(s3, off, 64);
    const u64 c0 = umin64(s0, b0);
    const u64 c1 = umin64(umin64(s1, b1), umax64(s0, b0));
    const u64 c2 = umin64(umin64(s2, b2),
                          umin64(umax64(s1, b0), umax64(s0, b1)));
    const u64 c3 = umin64(umin64(umin64(s3, b3), umax64(s2, b0)),
                          umin64(umax64(s0, b2), umax64(s1, b1)));
    s0 = c0; s1 = c1; s2 = c2; s3 = c3;
  }
  const u64 sel[4] = {s0, s1, s2, s3};

  // ---- phase 2: fp64 rescore; lane handles channels c = j*16 + l15
  float zq[16];
#pragma unroll
  for (int j = 0; j < 16; ++j) zq[j] = zs[j * 16 + l15][g];

  double bd = 1e300;
  int bi = 0x7fffffff;
#pragma unroll
  for (int c4 = 0; c4 < 4; ++c4) {
    const int idx = (int)(unsigned)(sel[c4] & 0xffffffffull);
    const float* er = emb + (size_t)idx * CD;
    double s = 0.0;
#pragma unroll
    for (int j = 0; j < 16; ++j) {
      const double d = (double)zq[j] - (double)er[j * 16 + l15];
      s += d * d;
    }
#pragma unroll
    for (int off = 1; off < 16; off <<= 1) s += __shfl_xor(s, off, 64);
    const bool better = (s < bd) || (s == bd && idx < bi);  // uniform in group
    if (better) { bd = s; bi = idx; }
  }

  // ---- phase 3: winner row -> slab (reused), then coalesced float2 stores
  __syncthreads();   // all phase-2 slab reads complete
  {
    const float* ew = emb + (size_t)bi * CD;
#pragma unroll
    for (int j = 0; j < 16; ++j) zs[j * 16 + l15][g] = ew[j * 16 + l15];
  }
  __syncthreads();
  {
    const int hw   = (lane & 31) * 2;
    const int csub = lane >> 5;
#pragma unroll
    for (int i = 0; i < 8; ++i) {
      const int c = wv * 16 + i * 2 + csub;
      const float2 v = *(const float2*)&zs[c][hw];
      *(float2*)(out + ((size_t)(b * CD + c)) * HW + hw0 + hw) = v;
    }
  }
}

extern "C" void kernel_launch(void* const* d_in, const int* in_sizes, int n_in,
                              void* d_out, int out_size, void* d_ws, size_t ws_size,
                              hipStream_t stream) {
  const float* z   = (const float*)d_in[0];
  const float* emb = (const float*)d_in[1];
  float* out = (float*)d_out;

  char* ws = (char*)d_ws;
  u16*   zTb  = (u16*)(ws + ZTB_OFF);
  u16*   embB = (u16*)(ws + EMBB_OFF);
  float* eH   = (float*)(ws + EH_OFF);
  u64*   cand = (u64*)(ws + CAND_OFF);

  k_prep<<<1280, 256, 0, stream>>>(z, emb, zTb, embB, eH);
  k_argmin<<<1024, 512, 0, stream>>>(zTb, embB, eH, cand);
  k_pick_out<<<256, 1024, 0, stream>>>(z, emb, cand, out);
}